// Round 1
// baseline (412.382 us; speedup 1.0000x reference)
//
#include <hip/hip_runtime.h>
#include <hip/hip_bf16.h>

#define NN 30000
#define DD 128
#define KK 32
#define OUTW 159   // 31 + 128

// ---------------- K1: z = h @ Wfc^T, plus fused dots s,d,zr0,zr1 ----------
__global__ __launch_bounds__(64) void k1_gemm(
    const float* __restrict__ h, const float* __restrict__ W,
    const float* __restrict__ Wa, const float* __restrict__ wr,
    float* __restrict__ z, float* __restrict__ s, float* __restrict__ dv,
    float* __restrict__ zr0, float* __restrict__ zr1) {
  int row = blockIdx.x * 64 + threadIdx.x;
  if (row >= NN) return;
  float hreg[DD];
  const float4* h4 = (const float4*)(h + (long)row * DD);
#pragma unroll
  for (int q = 0; q < DD / 4; q++) {
    float4 v = h4[q];
    hreg[4*q] = v.x; hreg[4*q+1] = v.y; hreg[4*q+2] = v.z; hreg[4*q+3] = v.w;
  }
  float sa = 0.f, da = 0.f, r0 = 0.f, r1 = 0.f;
  for (int j0 = 0; j0 < DD; j0 += 4) {
    float zj[4];
#pragma unroll
    for (int jj = 0; jj < 4; jj++) {
      int j = j0 + jj;
      const float* wrow = W + j * DD;   // uniform address -> scalar loads
      float a0 = 0.f, a1 = 0.f, a2 = 0.f, a3 = 0.f;
#pragma unroll
      for (int k = 0; k < DD; k += 4) {
        a0 += hreg[k]     * wrow[k];
        a1 += hreg[k + 1] * wrow[k + 1];
        a2 += hreg[k + 2] * wrow[k + 2];
        a3 += hreg[k + 3] * wrow[k + 3];
      }
      float zv = (a0 + a1) + (a2 + a3);
      zj[jj] = zv;
      sa += zv * Wa[j];        // a_src
      da += zv * Wa[DD + j];   // a_dst
      r0 += zv * wr[j];        // wr[0,0,0,:]
      r1 += zv * wr[DD + j];   // wr[0,0,1,:]
    }
    *(float4*)(z + (long)row * DD + j0) = make_float4(zj[0], zj[1], zj[2], zj[3]);
  }
  s[row] = sa; dv[row] = da; zr0[row] = r0; zr1[row] = r1;
}

// ---------------- K2: softmax + row outputs + col gather + BN partials ----
__global__ __launch_bounds__(256) void k2_main(
    const float* __restrict__ z, const float* __restrict__ s,
    const float* __restrict__ dv, const float* __restrict__ zr0,
    const float* __restrict__ zr1, const int* __restrict__ nbr,
    const float* __restrict__ wc, const float* __restrict__ brp,
    const float* __restrict__ bcp,
    float* __restrict__ out, float* __restrict__ partials) {
  __shared__ float red[4][4];
  int w = threadIdx.x >> 6, lane = threadIdx.x & 63;
  int i = blockIdx.x * 4 + w;          // 7500*4 == 30000 exactly
  float dvi = dv[i];
  float br0 = brp[0], bc0 = bcp[0];
  float pr = 0.f, pr2 = 0.f;
  float aw = 0.f; int base = 0;

  if (lane < KK) {
    int nk = nbr[i * KK + lane];
    float e = s[nk] + dvi;
    e = e > 0.f ? e : 0.01f * e;              // leaky_relu
    float mx = e;
#pragma unroll
    for (int o = 16; o; o >>= 1) mx = fmaxf(mx, __shfl_xor(mx, o, 32));
    float ex = __expf(e - mx);
    float sm = ex;
#pragma unroll
    for (int o = 16; o; o >>= 1) sm += __shfl_xor(sm, o, 32);
    float alpha = ex / sm;

    float t1 = alpha * zr1[nk];
    float t1n = __shfl_down(t1, 1, 32);       // j+1 term
    if (lane < KK - 1) {
      float rv = alpha * zr0[nk] + t1n + br0;
      out[(long)i * OUTW + lane] = rv;
      pr = rv; pr2 = rv * rv;
    }
    aw = alpha * wc[lane];
    base = nk * DD;
  }

  // col: all 64 lanes, each owns 2 of the 128 dims
  float ax = 0.f, ay = 0.f;
#pragma unroll
  for (int k = 0; k < KK; k++) {
    float a = __shfl(aw, k);
    int off = __shfl(base, k);
    float2 v = *(const float2*)(z + off + 2 * lane);
    ax += a * v.x; ay += a * v.y;
  }
  float c0 = ax + bc0, c1 = ay + bc0;
  long ob = (long)i * OUTW + 31 + 2 * lane;
  out[ob] = c0; out[ob + 1] = c1;
  float pc = c0 + c1, pc2 = c0 * c0 + c1 * c1;

  // wave reduce 4 values, then block reduce via LDS
#pragma unroll
  for (int o = 32; o; o >>= 1) {
    pr  += __shfl_xor(pr, o);  pr2 += __shfl_xor(pr2, o);
    pc  += __shfl_xor(pc, o);  pc2 += __shfl_xor(pc2, o);
  }
  if (lane == 0) { red[w][0] = pr; red[w][1] = pr2; red[w][2] = pc; red[w][3] = pc2; }
  __syncthreads();
  if (threadIdx.x < 4) {
    float v = red[0][threadIdx.x] + red[1][threadIdx.x] +
              red[2][threadIdx.x] + red[3][threadIdx.x];
    partials[(long)blockIdx.x * 4 + threadIdx.x] = v;
  }
}

// ---------------- K2b: reduce partials -> BN scale/shift -----------------
__global__ __launch_bounds__(256) void k2b_reduce(
    const float* __restrict__ partials, int nblocks,
    const float* __restrict__ gr, const float* __restrict__ betar,
    const float* __restrict__ gc, const float* __restrict__ betac,
    float* __restrict__ coef) {
  float v0 = 0.f, v1 = 0.f, v2 = 0.f, v3 = 0.f;
  for (int idx = threadIdx.x; idx < nblocks; idx += 256) {
    float4 p = ((const float4*)partials)[idx];
    v0 += p.x; v1 += p.y; v2 += p.z; v3 += p.w;
  }
#pragma unroll
  for (int o = 32; o; o >>= 1) {
    v0 += __shfl_xor(v0, o); v1 += __shfl_xor(v1, o);
    v2 += __shfl_xor(v2, o); v3 += __shfl_xor(v3, o);
  }
  __shared__ float red[4][4];
  int w = threadIdx.x >> 6, lane = threadIdx.x & 63;
  if (lane == 0) { red[w][0] = v0; red[w][1] = v1; red[w][2] = v2; red[w][3] = v3; }
  __syncthreads();
  if (threadIdx.x == 0) {
    float sr  = red[0][0] + red[1][0] + red[2][0] + red[3][0];
    float sr2 = red[0][1] + red[1][1] + red[2][1] + red[3][1];
    float sc  = red[0][2] + red[1][2] + red[2][2] + red[3][2];
    float sc2 = red[0][3] + red[1][3] + red[2][3] + red[3][3];
    const float cntR = (float)NN * 31.0f, cntC = (float)NN * 128.0f;
    float mR = sr / cntR,  vR = sr2 / cntR - mR * mR;
    float mC = sc / cntC,  vC = sc2 / cntC - mC * mC;
    float scR = gr[0] * rsqrtf(vR + 1e-5f);
    float scC = gc[0] * rsqrtf(vC + 1e-5f);
    coef[0] = scR; coef[1] = betar[0] - mR * scR;
    coef[2] = scC; coef[3] = betac[0] - mC * scC;
  }
}

// ---------------- K3: in-place BN + ReLU ----------------------------------
__global__ __launch_bounds__(256) void k3_bn(float* __restrict__ out,
                                             const float* __restrict__ coef) {
  float scR = coef[0], shR = coef[1], scC = coef[2], shC = coef[3];
  long idx = (long)blockIdx.x * 256 + threadIdx.x;
  const long total = (long)NN * OUTW;
  if (idx >= total) return;
  float x = out[idx];
  int j = (int)(idx % OUTW);
  float sc = j < 31 ? scR : scC;
  float sh = j < 31 ? shR : shC;
  out[idx] = fmaxf(sc * x + sh, 0.f);
}

extern "C" void kernel_launch(void* const* d_in, const int* in_sizes, int n_in,
                              void* d_out, int out_size, void* d_ws, size_t ws_size,
                              hipStream_t stream) {
  const float* h     = (const float*)d_in[0];
  const float* Wfc   = (const float*)d_in[1];
  const float* Wa    = (const float*)d_in[2];
  const float* wr    = (const float*)d_in[3];
  const float* br    = (const float*)d_in[4];
  const float* gr    = (const float*)d_in[5];
  const float* betar = (const float*)d_in[6];
  const float* wc    = (const float*)d_in[7];
  const float* bc    = (const float*)d_in[8];
  const float* gc    = (const float*)d_in[9];
  const float* betac = (const float*)d_in[10];
  const int*   nbr   = (const int*)d_in[11];
  float* out = (float*)d_out;

  float* ws   = (float*)d_ws;
  float* z    = ws;                      // NN*DD
  float* s    = z  + (long)NN * DD;      // NN
  float* dv   = s  + NN;                 // NN
  float* zr0  = dv + NN;                 // NN
  float* zr1  = zr0 + NN;                // NN
  float* partials = zr1 + NN;            // 7500*4
  float* coef = partials + NN;           // 4

  k1_gemm<<<(NN + 63) / 64, 64, 0, stream>>>(h, Wfc, Wa, wr, z, s, dv, zr0, zr1);
  k2_main<<<NN / 4, 256, 0, stream>>>(z, s, dv, zr0, zr1, nbr, wc, br, bc, out, partials);
  k2b_reduce<<<1, 256, 0, stream>>>(partials, NN / 4, gr, betar, gc, betac, coef);
  const long total = (long)NN * OUTW;
  k3_bn<<<(int)((total + 255) / 256), 256, 0, stream>>>(out, coef);
}

// Round 2
// 181.465 us; speedup vs baseline: 2.2725x; 2.2725x over previous
//
#include <hip/hip_runtime.h>
#include <hip/hip_bf16.h>

#define NN 30000
#define DD 128
#define KK 32
#define OUTW 159   // 31 + 128

// ---------------- K1: z = h @ Wfc^T (tiled fp32), fused dots s,d,zr0,zr1 --
// Block: 128 threads, tile M=64 x N=128, K staged in chunks of 32.
// Thread micro-tile: 8 rows (ty*8+rr) x 8 cols (tx+16*ci).
__global__ __launch_bounds__(128) void k1_gemm(
    const float* __restrict__ h, const float* __restrict__ W,
    const float* __restrict__ Wa, const float* __restrict__ wr,
    float* __restrict__ z, float* __restrict__ s, float* __restrict__ dv,
    float* __restrict__ zr0, float* __restrict__ zr1) {
  __shared__ float As[64 * 32];    // swizzled: (r,k)-> r*32 + 4*((k>>2)^((r>>3)&3)) + (k&3)
  __shared__ float Bs[128 * 36];   // (n,k) -> n*36 + k
  const int tid = threadIdx.x;
  const int tx = tid & 15, ty = tid >> 4;
  const int row0 = blockIdx.x * 64;

  float acc[8][8];
#pragma unroll
  for (int i = 0; i < 8; i++)
#pragma unroll
    for (int j = 0; j < 8; j++) acc[i][j] = 0.f;

  for (int kc = 0; kc < 4; kc++) {
    const int k0 = kc * 32;
    // stage A: 64 rows x 32 k  (4 float4 per thread)
#pragma unroll
    for (int q = 0; q < 4; q++) {
      int f = tid + 128 * q;
      int r = f >> 3, kq = f & 7;
      int row = row0 + r;
      float4 v = make_float4(0.f, 0.f, 0.f, 0.f);
      if (row < NN) v = *(const float4*)(h + (long)row * DD + k0 + kq * 4);
      *(float4*)(&As[r * 32 + 4 * (kq ^ ((r >> 3) & 3))]) = v;
    }
    // stage B: 128 n x 32 k  (8 float4 per thread)
#pragma unroll
    for (int q = 0; q < 8; q++) {
      int f = tid + 128 * q;
      int n = f >> 3, kq = f & 7;
      float4 v = *(const float4*)(W + n * DD + k0 + kq * 4);
      *(float4*)(&Bs[n * 36 + kq * 4]) = v;
    }
    __syncthreads();
#pragma unroll
    for (int k4 = 0; k4 < 8; k4++) {
      float4 a[8], b[8];
#pragma unroll
      for (int rr = 0; rr < 8; rr++) {
        int r = ty * 8 + rr;
        a[rr] = *(const float4*)(&As[r * 32 + 4 * (k4 ^ ((r >> 3) & 3))]);
      }
#pragma unroll
      for (int ci = 0; ci < 8; ci++)
        b[ci] = *(const float4*)(&Bs[(tx + 16 * ci) * 36 + k4 * 4]);
#pragma unroll
      for (int rr = 0; rr < 8; rr++)
#pragma unroll
        for (int ci = 0; ci < 8; ci++) {
          acc[rr][ci] += a[rr].x * b[ci].x + a[rr].y * b[ci].y +
                         a[rr].z * b[ci].z + a[rr].w * b[ci].w;
        }
    }
    __syncthreads();
  }

  // epilogue: store z, fused per-row dots with Wa / wr, reduce over tx lanes
#pragma unroll
  for (int rr = 0; rr < 8; rr++) {
    int row = row0 + ty * 8 + rr;
    float sa = 0.f, da = 0.f, r0s = 0.f, r1s = 0.f;
#pragma unroll
    for (int ci = 0; ci < 8; ci++) {
      int c = tx + 16 * ci;
      float zv = acc[rr][ci];
      sa  += zv * Wa[c];
      da  += zv * Wa[DD + c];
      r0s += zv * wr[c];
      r1s += zv * wr[DD + c];
      if (row < NN) z[(long)row * DD + c] = zv;
    }
#pragma unroll
    for (int o = 1; o < 16; o <<= 1) {
      sa  += __shfl_xor(sa, o);
      da  += __shfl_xor(da, o);
      r0s += __shfl_xor(r0s, o);
      r1s += __shfl_xor(r1s, o);
    }
    if (tx == 0 && row < NN) {
      s[row] = sa; dv[row] = da; zr0[row] = r0s; zr1[row] = r1s;
    }
  }
}

// ---------------- K2: softmax + row outputs + col gather + BN partials ----
__global__ __launch_bounds__(256) void k2_main(
    const float* __restrict__ z, const float* __restrict__ s,
    const float* __restrict__ dv, const float* __restrict__ zr0,
    const float* __restrict__ zr1, const int* __restrict__ nbr,
    const float* __restrict__ wc, const float* __restrict__ brp,
    const float* __restrict__ bcp,
    float* __restrict__ out, float* __restrict__ partials) {
  __shared__ float red[4][4];
  int w = threadIdx.x >> 6, lane = threadIdx.x & 63;
  int i = blockIdx.x * 4 + w;          // 7500*4 == 30000 exactly
  float dvi = dv[i];
  float br0 = brp[0], bc0 = bcp[0];
  float pr = 0.f, pr2 = 0.f;
  float aw = 0.f; int base = 0;

  if (lane < KK) {
    int nk = nbr[i * KK + lane];
    float e = s[nk] + dvi;
    e = e > 0.f ? e : 0.01f * e;              // leaky_relu
    float mx = e;
#pragma unroll
    for (int o = 16; o; o >>= 1) mx = fmaxf(mx, __shfl_xor(mx, o, 32));
    float ex = __expf(e - mx);
    float sm = ex;
#pragma unroll
    for (int o = 16; o; o >>= 1) sm += __shfl_xor(sm, o, 32);
    float alpha = ex / sm;

    float t1 = alpha * zr1[nk];
    float t1n = __shfl_down(t1, 1, 32);       // j+1 term
    if (lane < KK - 1) {
      float rv = alpha * zr0[nk] + t1n + br0;
      out[(long)i * OUTW + lane] = rv;
      pr = rv; pr2 = rv * rv;
    }
    aw = alpha * wc[lane];
    base = nk * DD;
  }

  // col: all 64 lanes, each owns 2 of the 128 dims
  float ax = 0.f, ay = 0.f;
#pragma unroll
  for (int k = 0; k < KK; k++) {
    float a = __shfl(aw, k);
    int off = __shfl(base, k);
    float2 v = *(const float2*)(z + off + 2 * lane);
    ax += a * v.x; ay += a * v.y;
  }
  float c0 = ax + bc0, c1 = ay + bc0;
  long ob = (long)i * OUTW + 31 + 2 * lane;
  out[ob] = c0; out[ob + 1] = c1;
  float pc = c0 + c1, pc2 = c0 * c0 + c1 * c1;

  // wave reduce 4 values, then block reduce via LDS
#pragma unroll
  for (int o = 32; o; o >>= 1) {
    pr  += __shfl_xor(pr, o);  pr2 += __shfl_xor(pr2, o);
    pc  += __shfl_xor(pc, o);  pc2 += __shfl_xor(pc2, o);
  }
  if (lane == 0) { red[w][0] = pr; red[w][1] = pr2; red[w][2] = pc; red[w][3] = pc2; }
  __syncthreads();
  if (threadIdx.x < 4) {
    float v = red[0][threadIdx.x] + red[1][threadIdx.x] +
              red[2][threadIdx.x] + red[3][threadIdx.x];
    partials[(long)blockIdx.x * 4 + threadIdx.x] = v;
  }
}

// ---------------- K2b: reduce partials -> BN scale/shift -----------------
__global__ __launch_bounds__(256) void k2b_reduce(
    const float* __restrict__ partials, int nblocks,
    const float* __restrict__ gr, const float* __restrict__ betar,
    const float* __restrict__ gc, const float* __restrict__ betac,
    float* __restrict__ coef) {
  float v0 = 0.f, v1 = 0.f, v2 = 0.f, v3 = 0.f;
  for (int idx = threadIdx.x; idx < nblocks; idx += 256) {
    float4 p = ((const float4*)partials)[idx];
    v0 += p.x; v1 += p.y; v2 += p.z; v3 += p.w;
  }
#pragma unroll
  for (int o = 32; o; o >>= 1) {
    v0 += __shfl_xor(v0, o); v1 += __shfl_xor(v1, o);
    v2 += __shfl_xor(v2, o); v3 += __shfl_xor(v3, o);
  }
  __shared__ float red[4][4];
  int w = threadIdx.x >> 6, lane = threadIdx.x & 63;
  if (lane == 0) { red[w][0] = v0; red[w][1] = v1; red[w][2] = v2; red[w][3] = v3; }
  __syncthreads();
  if (threadIdx.x == 0) {
    float sr  = red[0][0] + red[1][0] + red[2][0] + red[3][0];
    float sr2 = red[0][1] + red[1][1] + red[2][1] + red[3][1];
    float sc  = red[0][2] + red[1][2] + red[2][2] + red[3][2];
    float sc2 = red[0][3] + red[1][3] + red[2][3] + red[3][3];
    const float cntR = (float)NN * 31.0f, cntC = (float)NN * 128.0f;
    float mR = sr / cntR,  vR = sr2 / cntR - mR * mR;
    float mC = sc / cntC,  vC = sc2 / cntC - mC * mC;
    float scR = gr[0] * rsqrtf(vR + 1e-5f);
    float scC = gc[0] * rsqrtf(vC + 1e-5f);
    coef[0] = scR; coef[1] = betar[0] - mR * scR;
    coef[2] = scC; coef[3] = betac[0] - mC * scC;
  }
}

// ---------------- K3: in-place BN + ReLU ----------------------------------
__global__ __launch_bounds__(256) void k3_bn(float* __restrict__ out,
                                             const float* __restrict__ coef) {
  float scR = coef[0], shR = coef[1], scC = coef[2], shC = coef[3];
  long idx = (long)blockIdx.x * 256 + threadIdx.x;
  const long total = (long)NN * OUTW;
  if (idx >= total) return;
  float x = out[idx];
  int j = (int)(idx % OUTW);
  float sc = j < 31 ? scR : scC;
  float sh = j < 31 ? shR : shC;
  out[idx] = fmaxf(sc * x + sh, 0.f);
}

extern "C" void kernel_launch(void* const* d_in, const int* in_sizes, int n_in,
                              void* d_out, int out_size, void* d_ws, size_t ws_size,
                              hipStream_t stream) {
  const float* h     = (const float*)d_in[0];
  const float* Wfc   = (const float*)d_in[1];
  const float* Wa    = (const float*)d_in[2];
  const float* wr    = (const float*)d_in[3];
  const float* br    = (const float*)d_in[4];
  const float* gr    = (const float*)d_in[5];
  const float* betar = (const float*)d_in[6];
  const float* wc    = (const float*)d_in[7];
  const float* bc    = (const float*)d_in[8];
  const float* gc    = (const float*)d_in[9];
  const float* betac = (const float*)d_in[10];
  const int*   nbr   = (const int*)d_in[11];
  float* out = (float*)d_out;

  float* ws   = (float*)d_ws;
  float* z    = ws;                      // NN*DD
  float* s    = z  + (long)NN * DD;      // NN
  float* dv   = s  + NN;                 // NN
  float* zr0  = dv + NN;                 // NN
  float* zr1  = zr0 + NN;                // NN
  float* partials = zr1 + NN;            // 7500*4
  float* coef = partials + NN;           // 4

  k1_gemm<<<(NN + 63) / 64, 128, 0, stream>>>(h, Wfc, Wa, wr, z, s, dv, zr0, zr1);
  k2_main<<<NN / 4, 256, 0, stream>>>(z, s, dv, zr0, zr1, nbr, wc, br, bc, out, partials);
  k2b_reduce<<<1, 256, 0, stream>>>(partials, NN / 4, gr, betar, gc, betac, coef);
  const long total = (long)NN * OUTW;
  k3_bn<<<(int)((total + 255) / 256), 256, 0, stream>>>(out, coef);
}

// Round 3
// 114.230 us; speedup vs baseline: 3.6101x; 1.5886x over previous
//
#include <hip/hip_runtime.h>
#include <hip/hip_bf16.h>

#define NN 30000
#define DD 128
#define KK 32
#define OUTW 159   // 31 + 128

// ---------------- K1: z = h @ Wfc^T (tiled fp32), fused dots s,d,zr0,zr1 --
// Block: 256 threads, tile M=32 x N=128, K staged in chunks of 32.
// Thread micro-tile: 2 rows (ty*2+rr) x 8 cols (tx+16*ci).  ~80 VGPR, no spill.
__global__ __launch_bounds__(256) void k1_gemm(
    const float* __restrict__ h, const float* __restrict__ W,
    const float* __restrict__ Wa, const float* __restrict__ wr,
    float* __restrict__ z, float* __restrict__ s, float* __restrict__ dv,
    float* __restrict__ zr0, float* __restrict__ zr1) {
  __shared__ float As[32 * 32];    // swizzled: (r,k)-> r*32 + 4*((k>>2)^((r>>1)&3)) + (k&3)
  __shared__ float Bs[128 * 36];   // (n,k) -> n*36 + k   (stride 36: 2-way, free)
  const int tid = threadIdx.x;
  const int tx = tid & 15, ty = tid >> 4;
  const int row0 = blockIdx.x * 32;

  float acc[2][8];
#pragma unroll
  for (int i = 0; i < 2; i++)
#pragma unroll
    for (int j = 0; j < 8; j++) acc[i][j] = 0.f;

  for (int kc = 0; kc < 4; kc++) {
    const int k0 = kc * 32;
    // stage A: 32 rows x 32 k  (1 float4 per thread)
    {
      int r = tid >> 3, kq = tid & 7;
      int row = row0 + r;
      float4 v = make_float4(0.f, 0.f, 0.f, 0.f);
      if (row < NN) v = *(const float4*)(h + (long)row * DD + k0 + kq * 4);
      *(float4*)(&As[r * 32 + 4 * (kq ^ ((r >> 1) & 3))]) = v;
    }
    // stage B: 128 n x 32 k  (4 float4 per thread)
#pragma unroll
    for (int q = 0; q < 4; q++) {
      int f = tid + 256 * q;
      int n = f >> 3, kq = f & 7;
      float4 v = *(const float4*)(W + n * DD + k0 + kq * 4);
      *(float4*)(&Bs[n * 36 + kq * 4]) = v;
    }
    __syncthreads();
#pragma unroll
    for (int k4 = 0; k4 < 8; k4++) {
      float4 a[2], b[8];
#pragma unroll
      for (int rr = 0; rr < 2; rr++) {
        int r = ty * 2 + rr;
        a[rr] = *(const float4*)(&As[r * 32 + 4 * (k4 ^ ((r >> 1) & 3))]);
      }
#pragma unroll
      for (int ci = 0; ci < 8; ci++)
        b[ci] = *(const float4*)(&Bs[(tx + 16 * ci) * 36 + k4 * 4]);
#pragma unroll
      for (int rr = 0; rr < 2; rr++)
#pragma unroll
        for (int ci = 0; ci < 8; ci++) {
          acc[rr][ci] += a[rr].x * b[ci].x + a[rr].y * b[ci].y +
                         a[rr].z * b[ci].z + a[rr].w * b[ci].w;
        }
    }
    __syncthreads();
  }

  // epilogue: store z, fused per-row dots with Wa / wr, reduce over tx lanes
#pragma unroll
  for (int rr = 0; rr < 2; rr++) {
    int row = row0 + ty * 2 + rr;
    float sa = 0.f, da = 0.f, r0s = 0.f, r1s = 0.f;
#pragma unroll
    for (int ci = 0; ci < 8; ci++) {
      int c = tx + 16 * ci;
      float zv = acc[rr][ci];
      sa  += zv * Wa[c];
      da  += zv * Wa[DD + c];
      r0s += zv * wr[c];
      r1s += zv * wr[DD + c];
      if (row < NN) z[(long)row * DD + c] = zv;
    }
#pragma unroll
    for (int o = 1; o < 16; o <<= 1) {   // xor within aligned 16-lane groups
      sa  += __shfl_xor(sa, o);
      da  += __shfl_xor(da, o);
      r0s += __shfl_xor(r0s, o);
      r1s += __shfl_xor(r1s, o);
    }
    if (tx == 0 && row < NN) {
      s[row] = sa; dv[row] = da; zr0[row] = r0s; zr1[row] = r1s;
    }
  }
}

// ---------------- K2: softmax + row outputs + col gather + BN partials ----
__global__ __launch_bounds__(256) void k2_main(
    const float* __restrict__ z, const float* __restrict__ s,
    const float* __restrict__ dv, const float* __restrict__ zr0,
    const float* __restrict__ zr1, const int* __restrict__ nbr,
    const float* __restrict__ wc, const float* __restrict__ brp,
    const float* __restrict__ bcp,
    float* __restrict__ out, float* __restrict__ partials) {
  __shared__ float red[4][4];
  int w = threadIdx.x >> 6, lane = threadIdx.x & 63;
  int i = blockIdx.x * 4 + w;          // 7500*4 == 30000 exactly
  float dvi = dv[i];
  float br0 = brp[0], bc0 = bcp[0];
  float pr = 0.f, pr2 = 0.f;
  float aw = 0.f; int base = 0;

  if (lane < KK) {
    int nk = nbr[i * KK + lane];
    float e = s[nk] + dvi;
    e = e > 0.f ? e : 0.01f * e;              // leaky_relu
    float mx = e;
#pragma unroll
    for (int o = 16; o; o >>= 1) mx = fmaxf(mx, __shfl_xor(mx, o, 32));
    float ex = __expf(e - mx);
    float sm = ex;
#pragma unroll
    for (int o = 16; o; o >>= 1) sm += __shfl_xor(sm, o, 32);
    float alpha = ex / sm;

    float t1 = alpha * zr1[nk];
    float t1n = __shfl_down(t1, 1, 32);       // j+1 term
    if (lane < KK - 1) {
      float rv = alpha * zr0[nk] + t1n + br0;
      out[(long)i * OUTW + lane] = rv;
      pr = rv; pr2 = rv * rv;
    }
    aw = alpha * wc[lane];
    base = nk * DD;
  }

  // col: all 64 lanes, each owns 2 of the 128 dims
  float ax = 0.f, ay = 0.f;
#pragma unroll
  for (int k = 0; k < KK; k++) {
    float a = __shfl(aw, k);
    int off = __shfl(base, k);
    float2 v = *(const float2*)(z + off + 2 * lane);
    ax += a * v.x; ay += a * v.y;
  }
  float c0 = ax + bc0, c1 = ay + bc0;
  long ob = (long)i * OUTW + 31 + 2 * lane;
  out[ob] = c0; out[ob + 1] = c1;
  float pc = c0 + c1, pc2 = c0 * c0 + c1 * c1;

  // wave reduce 4 values, then block reduce via LDS
#pragma unroll
  for (int o = 32; o; o >>= 1) {
    pr  += __shfl_xor(pr, o);  pr2 += __shfl_xor(pr2, o);
    pc  += __shfl_xor(pc, o);  pc2 += __shfl_xor(pc2, o);
  }
  if (lane == 0) { red[w][0] = pr; red[w][1] = pr2; red[w][2] = pc; red[w][3] = pc2; }
  __syncthreads();
  if (threadIdx.x < 4) {
    float v = red[0][threadIdx.x] + red[1][threadIdx.x] +
              red[2][threadIdx.x] + red[3][threadIdx.x];
    partials[(long)blockIdx.x * 4 + threadIdx.x] = v;
  }
}

// ---------------- K2b: reduce partials -> BN scale/shift -----------------
__global__ __launch_bounds__(256) void k2b_reduce(
    const float* __restrict__ partials, int nblocks,
    const float* __restrict__ gr, const float* __restrict__ betar,
    const float* __restrict__ gc, const float* __restrict__ betac,
    float* __restrict__ coef) {
  float v0 = 0.f, v1 = 0.f, v2 = 0.f, v3 = 0.f;
  for (int idx = threadIdx.x; idx < nblocks; idx += 256) {
    float4 p = ((const float4*)partials)[idx];
    v0 += p.x; v1 += p.y; v2 += p.z; v3 += p.w;
  }
#pragma unroll
  for (int o = 32; o; o >>= 1) {
    v0 += __shfl_xor(v0, o); v1 += __shfl_xor(v1, o);
    v2 += __shfl_xor(v2, o); v3 += __shfl_xor(v3, o);
  }
  __shared__ float red[4][4];
  int w = threadIdx.x >> 6, lane = threadIdx.x & 63;
  if (lane == 0) { red[w][0] = v0; red[w][1] = v1; red[w][2] = v2; red[w][3] = v3; }
  __syncthreads();
  if (threadIdx.x == 0) {
    float sr  = red[0][0] + red[1][0] + red[2][0] + red[3][0];
    float sr2 = red[0][1] + red[1][1] + red[2][1] + red[3][1];
    float sc  = red[0][2] + red[1][2] + red[2][2] + red[3][2];
    float sc2 = red[0][3] + red[1][3] + red[2][3] + red[3][3];
    const float cntR = (float)NN * 31.0f, cntC = (float)NN * 128.0f;
    float mR = sr / cntR,  vR = sr2 / cntR - mR * mR;
    float mC = sc / cntC,  vC = sc2 / cntC - mC * mC;
    float scR = gr[0] * rsqrtf(vR + 1e-5f);
    float scC = gc[0] * rsqrtf(vC + 1e-5f);
    coef[0] = scR; coef[1] = betar[0] - mR * scR;
    coef[2] = scC; coef[3] = betac[0] - mC * scC;
  }
}

// ---------------- K3: in-place BN + ReLU ----------------------------------
__global__ __launch_bounds__(256) void k3_bn(float* __restrict__ out,
                                             const float* __restrict__ coef) {
  float scR = coef[0], shR = coef[1], scC = coef[2], shC = coef[3];
  long idx = (long)blockIdx.x * 256 + threadIdx.x;
  const long total = (long)NN * OUTW;
  if (idx >= total) return;
  float x = out[idx];
  int j = (int)(idx % OUTW);
  float sc = j < 31 ? scR : scC;
  float sh = j < 31 ? shR : shC;
  out[idx] = fmaxf(sc * x + sh, 0.f);
}

extern "C" void kernel_launch(void* const* d_in, const int* in_sizes, int n_in,
                              void* d_out, int out_size, void* d_ws, size_t ws_size,
                              hipStream_t stream) {
  const float* h     = (const float*)d_in[0];
  const float* Wfc   = (const float*)d_in[1];
  const float* Wa    = (const float*)d_in[2];
  const float* wr    = (const float*)d_in[3];
  const float* br    = (const float*)d_in[4];
  const float* gr    = (const float*)d_in[5];
  const float* betar = (const float*)d_in[6];
  const float* wc    = (const float*)d_in[7];
  const float* bc    = (const float*)d_in[8];
  const float* gc    = (const float*)d_in[9];
  const float* betac = (const float*)d_in[10];
  const int*   nbr   = (const int*)d_in[11];
  float* out = (float*)d_out;

  float* ws   = (float*)d_ws;
  float* z    = ws;                      // NN*DD
  float* s    = z  + (long)NN * DD;      // NN
  float* dv   = s  + NN;                 // NN
  float* zr0  = dv + NN;                 // NN
  float* zr1  = zr0 + NN;                // NN
  float* partials = zr1 + NN;            // 7500*4
  float* coef = partials + NN;           // 4

  k1_gemm<<<(NN + 31) / 32, 256, 0, stream>>>(h, Wfc, Wa, wr, z, s, dv, zr0, zr1);
  k2_main<<<NN / 4, 256, 0, stream>>>(z, s, dv, zr0, zr1, nbr, wc, br, bc, out, partials);
  k2b_reduce<<<1, 256, 0, stream>>>(partials, NN / 4, gr, betar, gc, betac, coef);
  const long total = (long)NN * OUTW;
  k3_bn<<<(int)((total + 255) / 256), 256, 0, stream>>>(out, coef);
}

// Round 4
// 72.081 us; speedup vs baseline: 5.7211x; 1.5847x over previous
//
#include <hip/hip_runtime.h>
#include <hip/hip_fp16.h>

#define NN 30000
#define DD 128
#define KK 32
#define OUTW 159   // 31 + 128

typedef __attribute__((ext_vector_type(8))) short bf16x8;
typedef __attribute__((ext_vector_type(4))) float f32x4;

static __device__ inline short f2bf(float f) {
  union { float f; unsigned u; } x; x.f = f;
  unsigned r = x.u + 0x7fffu + ((x.u >> 16) & 1u);   // RNE
  return (short)(r >> 16);
}

// ---------------- K1: z = h @ Wfc^T via MFMA bf16; fused dots; z -> fp16 --
// Block: 256 threads (4 waves), tile M=64 x N=128, K=128 fully staged.
// LDS: A 64x128 bf16 (16KB, XOR-swizzled) + B(=W) 128x128 bf16 (32KB, swizzled).
__global__ __launch_bounds__(256) void k1_gemm(
    const float* __restrict__ h, const float* __restrict__ W,
    const float* __restrict__ Wa, const float* __restrict__ wr,
    __half* __restrict__ z, float* __restrict__ s, float* __restrict__ dv,
    float* __restrict__ zr0, float* __restrict__ zr1) {
  __shared__ char smem[48 * 1024];
  short* As = (short*)smem;               // 64*128 bf16, row stride 256B
  short* Bs = (short*)(smem + 16 * 1024); // 128*128 bf16, row stride 256B
  const int tid = threadIdx.x;
  const int row0 = blockIdx.x * 64;

  // ---- stage A (h tile, fp32 -> bf16) : 4 chunks of 8 per thread
#pragma unroll
  for (int q = 0; q < 4; q++) {
    int idx = q * 256 + tid;
    int r = idx >> 4, kq = idx & 15;      // lanes 0-15 cover one row contiguously
    int row = row0 + r;
    float v[8];
    if (row < NN) {
      float4 v0 = *(const float4*)(h + (long)row * DD + kq * 8);
      float4 v1 = *(const float4*)(h + (long)row * DD + kq * 8 + 4);
      v[0]=v0.x; v[1]=v0.y; v[2]=v0.z; v[3]=v0.w;
      v[4]=v1.x; v[5]=v1.y; v[6]=v1.z; v[7]=v1.w;
    } else {
#pragma unroll
      for (int j = 0; j < 8; j++) v[j] = 0.f;
    }
    bf16x8 b;
#pragma unroll
    for (int j = 0; j < 8; j++) b[j] = f2bf(v[j]);
    *(bf16x8*)((char*)As + r * 256 + ((kq * 16) ^ ((r & 7) << 4))) = b;
  }
  // ---- stage B (whole W, fp32 -> bf16) : 8 chunks of 8 per thread
#pragma unroll
  for (int q = 0; q < 8; q++) {
    int idx = q * 256 + tid;
    int j0 = idx >> 4, kq = idx & 15;     // j0 = output col (W row)
    float4 v0 = *(const float4*)(W + (long)j0 * DD + kq * 8);
    float4 v1 = *(const float4*)(W + (long)j0 * DD + kq * 8 + 4);
    float v[8] = {v0.x, v0.y, v0.z, v0.w, v1.x, v1.y, v1.z, v1.w};
    bf16x8 b;
#pragma unroll
    for (int jj = 0; jj < 8; jj++) b[jj] = f2bf(v[jj]);
    *(bf16x8*)((char*)Bs + j0 * 256 + ((kq * 16) ^ ((j0 & 7) << 4))) = b;
  }
  __syncthreads();

  const int wid = tid >> 6, lane = tid & 63;
  const int la = lane & 15, lb = lane >> 4;   // A row / B col = la; k-group = lb

  // A fragments: row = wid*16+la, k = kc*32 + lb*8 + [0..8)
  bf16x8 afr[4];
#pragma unroll
  for (int kc = 0; kc < 4; kc++) {
    int r = wid * 16 + la;
    int cb2 = (kc * 32 + lb * 8) * 2;
    afr[kc] = *(bf16x8*)((char*)As + r * 256 + (cb2 ^ ((la & 7) << 4)));
  }

  f32x4 acc[8];
#pragma unroll
  for (int cb = 0; cb < 8; cb++) acc[cb] = (f32x4){0.f, 0.f, 0.f, 0.f};

#pragma unroll
  for (int cb = 0; cb < 8; cb++) {
    int j = cb * 16 + la;
#pragma unroll
    for (int kc = 0; kc < 4; kc++) {
      int cb2 = (kc * 32 + lb * 8) * 2;
      bf16x8 bfr = *(bf16x8*)((char*)Bs + j * 256 + (cb2 ^ ((la & 7) << 4)));
      acc[cb] = __builtin_amdgcn_mfma_f32_16x16x32_bf16(afr[kc], bfr, acc[cb], 0, 0, 0);
    }
  }

  // ---- fused per-row dots: s, dv, zr0, zr1 (reduce over cols = la lanes)
  float sa[4] = {0,0,0,0}, da[4] = {0,0,0,0}, r0s[4] = {0,0,0,0}, r1s[4] = {0,0,0,0};
#pragma unroll
  for (int cb = 0; cb < 8; cb++) {
    int c = cb * 16 + la;
    float wa0 = Wa[c], wa1 = Wa[DD + c], w0 = wr[c], w1 = wr[DD + c];
#pragma unroll
    for (int rg = 0; rg < 4; rg++) {
      float zv = acc[cb][rg];
      sa[rg]  += zv * wa0; da[rg]  += zv * wa1;
      r0s[rg] += zv * w0;  r1s[rg] += zv * w1;
    }
  }
#pragma unroll
  for (int rg = 0; rg < 4; rg++) {
#pragma unroll
    for (int o = 1; o < 16; o <<= 1) {
      sa[rg]  += __shfl_xor(sa[rg], o);
      da[rg]  += __shfl_xor(da[rg], o);
      r0s[rg] += __shfl_xor(r0s[rg], o);
      r1s[rg] += __shfl_xor(r1s[rg], o);
    }
    int row = row0 + wid * 16 + lb * 4 + rg;
    if (la == 0 && row < NN) {
      s[row] = sa[rg]; dv[row] = da[rg]; zr0[row] = r0s[rg]; zr1[row] = r1s[rg];
    }
  }

  // ---- z -> fp16 via LDS transpose (stride 132 halfs to avoid conflicts)
  __syncthreads();
  __half* zl = (__half*)smem;             // 64 x 132 halfs = 16.5KB
#pragma unroll
  for (int cb = 0; cb < 8; cb++) {
#pragma unroll
    for (int rg = 0; rg < 4; rg++) {
      int r = wid * 16 + lb * 4 + rg, c = cb * 16 + la;
      zl[r * 132 + c] = __float2half(acc[cb][rg]);
    }
  }
  __syncthreads();
  {
    int r = tid >> 2, c0 = (tid & 3) * 32;
    int row = row0 + r;
    if (row < NN) {
      const __half* src = zl + r * 132 + c0;
      int4 a0 = *(const int4*)(src);
      int4 a1 = *(const int4*)(src + 8);
      int4 a2 = *(const int4*)(src + 16);
      int4 a3 = *(const int4*)(src + 24);
      __half* dst = z + (long)row * DD + c0;
      *(int4*)(dst)      = a0;
      *(int4*)(dst + 8)  = a1;
      *(int4*)(dst + 16) = a2;
      *(int4*)(dst + 24) = a3;
    }
  }
}

// ---------------- K2: softmax + row outputs + col gather (fp16) + BN partials
__global__ __launch_bounds__(256) void k2_main(
    const __half* __restrict__ z, const float* __restrict__ s,
    const float* __restrict__ dv, const float* __restrict__ zr0,
    const float* __restrict__ zr1, const int* __restrict__ nbr,
    const float* __restrict__ wc, const float* __restrict__ brp,
    const float* __restrict__ bcp,
    float* __restrict__ out, float* __restrict__ partials) {
  __shared__ float red[4][4];
  int w = threadIdx.x >> 6, lane = threadIdx.x & 63;
  int i = blockIdx.x * 4 + w;          // 7500*4 == 30000 exactly
  float dvi = dv[i];
  float br0 = brp[0], bc0 = bcp[0];
  float pr = 0.f, pr2 = 0.f;
  float aw = 0.f; int base = 0;

  if (lane < KK) {
    int nk = nbr[i * KK + lane];
    float e = s[nk] + dvi;
    e = e > 0.f ? e : 0.01f * e;              // leaky_relu
    float mx = e;
#pragma unroll
    for (int o = 16; o; o >>= 1) mx = fmaxf(mx, __shfl_xor(mx, o, 32));
    float ex = __expf(e - mx);
    float sm = ex;
#pragma unroll
    for (int o = 16; o; o >>= 1) sm += __shfl_xor(sm, o, 32);
    float alpha = ex / sm;

    float t1 = alpha * zr1[nk];
    float t1n = __shfl_down(t1, 1, 32);       // j+1 term
    if (lane < KK - 1) {
      float rv = alpha * zr0[nk] + t1n + br0;
      out[(long)i * OUTW + lane] = rv;
      pr = rv; pr2 = rv * rv;
    }
    aw = alpha * wc[lane];
    base = nk * (DD / 2);                     // in __half2 units
  }

  // col: all 64 lanes, each owns 2 of the 128 dims (one __half2)
  const __half2* z2 = (const __half2*)z;
  float ax = 0.f, ay = 0.f;
#pragma unroll
  for (int k = 0; k < KK; k++) {
    float a = __shfl(aw, k);
    int off = __shfl(base, k);
    float2 v = __half22float2(z2[off + lane]);
    ax += a * v.x; ay += a * v.y;
  }
  float c0 = ax + bc0, c1 = ay + bc0;
  long ob = (long)i * OUTW + 31 + 2 * lane;
  out[ob] = c0; out[ob + 1] = c1;
  float pc = c0 + c1, pc2 = c0 * c0 + c1 * c1;

  // wave reduce 4 values, then block reduce via LDS
#pragma unroll
  for (int o = 32; o; o >>= 1) {
    pr  += __shfl_xor(pr, o);  pr2 += __shfl_xor(pr2, o);
    pc  += __shfl_xor(pc, o);  pc2 += __shfl_xor(pc2, o);
  }
  if (lane == 0) { red[w][0] = pr; red[w][1] = pr2; red[w][2] = pc; red[w][3] = pc2; }
  __syncthreads();
  if (threadIdx.x < 4) {
    float v = red[0][threadIdx.x] + red[1][threadIdx.x] +
              red[2][threadIdx.x] + red[3][threadIdx.x];
    partials[(long)blockIdx.x * 4 + threadIdx.x] = v;
  }
}

// ---------------- K2b: reduce partials -> BN scale/shift -----------------
__global__ __launch_bounds__(256) void k2b_reduce(
    const float* __restrict__ partials, int nblocks,
    const float* __restrict__ gr, const float* __restrict__ betar,
    const float* __restrict__ gc, const float* __restrict__ betac,
    float* __restrict__ coef) {
  float v0 = 0.f, v1 = 0.f, v2 = 0.f, v3 = 0.f;
  for (int idx = threadIdx.x; idx < nblocks; idx += 256) {
    float4 p = ((const float4*)partials)[idx];
    v0 += p.x; v1 += p.y; v2 += p.z; v3 += p.w;
  }
#pragma unroll
  for (int o = 32; o; o >>= 1) {
    v0 += __shfl_xor(v0, o); v1 += __shfl_xor(v1, o);
    v2 += __shfl_xor(v2, o); v3 += __shfl_xor(v3, o);
  }
  __shared__ float red[4][4];
  int w = threadIdx.x >> 6, lane = threadIdx.x & 63;
  if (lane == 0) { red[w][0] = v0; red[w][1] = v1; red[w][2] = v2; red[w][3] = v3; }
  __syncthreads();
  if (threadIdx.x == 0) {
    float sr  = red[0][0] + red[1][0] + red[2][0] + red[3][0];
    float sr2 = red[0][1] + red[1][1] + red[2][1] + red[3][1];
    float sc  = red[0][2] + red[1][2] + red[2][2] + red[3][2];
    float sc2 = red[0][3] + red[1][3] + red[2][3] + red[3][3];
    const float cntR = (float)NN * 31.0f, cntC = (float)NN * 128.0f;
    float mR = sr / cntR,  vR = sr2 / cntR - mR * mR;
    float mC = sc / cntC,  vC = sc2 / cntC - mC * mC;
    float scR = gr[0] * rsqrtf(vR + 1e-5f);
    float scC = gc[0] * rsqrtf(vC + 1e-5f);
    coef[0] = scR; coef[1] = betar[0] - mR * scR;
    coef[2] = scC; coef[3] = betac[0] - mC * scC;
  }
}

// ---------------- K3: in-place BN + ReLU ----------------------------------
__global__ __launch_bounds__(256) void k3_bn(float* __restrict__ out,
                                             const float* __restrict__ coef) {
  float scR = coef[0], shR = coef[1], scC = coef[2], shC = coef[3];
  long idx = (long)blockIdx.x * 256 + threadIdx.x;
  const long total = (long)NN * OUTW;
  if (idx >= total) return;
  float x = out[idx];
  int j = (int)(idx % OUTW);
  float sc = j < 31 ? scR : scC;
  float sh = j < 31 ? shR : shC;
  out[idx] = fmaxf(sc * x + sh, 0.f);
}

extern "C" void kernel_launch(void* const* d_in, const int* in_sizes, int n_in,
                              void* d_out, int out_size, void* d_ws, size_t ws_size,
                              hipStream_t stream) {
  const float* h     = (const float*)d_in[0];
  const float* Wfc   = (const float*)d_in[1];
  const float* Wa    = (const float*)d_in[2];
  const float* wr    = (const float*)d_in[3];
  const float* br    = (const float*)d_in[4];
  const float* gr    = (const float*)d_in[5];
  const float* betar = (const float*)d_in[6];
  const float* wc    = (const float*)d_in[7];
  const float* bc    = (const float*)d_in[8];
  const float* gc    = (const float*)d_in[9];
  const float* betac = (const float*)d_in[10];
  const int*   nbr   = (const int*)d_in[11];
  float* out = (float*)d_out;

  float* ws   = (float*)d_ws;
  __half* z   = (__half*)ws;             // NN*DD halfs = NN*DD/2 floats
  float* s    = ws + (long)NN * DD / 2;  // NN
  float* dv   = s  + NN;                 // NN
  float* zr0  = dv + NN;                 // NN
  float* zr1  = zr0 + NN;                // NN
  float* partials = zr1 + NN;            // 7500*4
  float* coef = partials + NN;           // 4

  k1_gemm<<<(NN + 63) / 64, 256, 0, stream>>>(h, Wfc, Wa, wr, z, s, dv, zr0, zr1);
  k2_main<<<NN / 4, 256, 0, stream>>>(z, s, dv, zr0, zr1, nbr, wc, br, bc, out, partials);
  k2b_reduce<<<1, 256, 0, stream>>>(partials, NN / 4, gr, betar, gc, betac, coef);
  const long total = (long)NN * OUTW;
  k3_bn<<<(int)((total + 255) / 256), 256, 0, stream>>>(out, coef);
}

// Round 6
// 63.931 us; speedup vs baseline: 6.4504x; 1.1275x over previous
//
#include <hip/hip_runtime.h>
#include <hip/hip_fp16.h>

#define NN 30000
#define DD 128
#define KK 32
#define OUTW 159   // 31 + 128
#define K2BLKS 1875   // 16 nodes per block
#define K3BLKS 1024

typedef __attribute__((ext_vector_type(8))) short bf16x8;
typedef __attribute__((ext_vector_type(4))) float f32x4;

static __device__ inline short f2bf(float f) {
  union { float f; unsigned u; } x; x.f = f;
  unsigned r = x.u + 0x7fffu + ((x.u >> 16) & 1u);   // RNE
  return (short)(r >> 16);
}

// ---------------- K1: z = h @ Wfc^T via MFMA bf16; fused dots; z -> fp16 --
__global__ __launch_bounds__(256) void k1_gemm(
    const float* __restrict__ h, const float* __restrict__ W,
    const float* __restrict__ Wa, const float* __restrict__ wr,
    __half* __restrict__ z, float* __restrict__ s, float* __restrict__ dv,
    float* __restrict__ zr0, float* __restrict__ zr1) {
  __shared__ char smem[48 * 1024];
  short* As = (short*)smem;               // 64*128 bf16, row stride 256B
  short* Bs = (short*)(smem + 16 * 1024); // 128*128 bf16, row stride 256B
  const int tid = threadIdx.x;
  const int row0 = blockIdx.x * 64;

#pragma unroll
  for (int q = 0; q < 4; q++) {
    int idx = q * 256 + tid;
    int r = idx >> 4, kq = idx & 15;
    int row = row0 + r;
    float v[8];
    if (row < NN) {
      float4 v0 = *(const float4*)(h + (long)row * DD + kq * 8);
      float4 v1 = *(const float4*)(h + (long)row * DD + kq * 8 + 4);
      v[0]=v0.x; v[1]=v0.y; v[2]=v0.z; v[3]=v0.w;
      v[4]=v1.x; v[5]=v1.y; v[6]=v1.z; v[7]=v1.w;
    } else {
#pragma unroll
      for (int j = 0; j < 8; j++) v[j] = 0.f;
    }
    bf16x8 b;
#pragma unroll
    for (int j = 0; j < 8; j++) b[j] = f2bf(v[j]);
    *(bf16x8*)((char*)As + r * 256 + ((kq * 16) ^ ((r & 7) << 4))) = b;
  }
#pragma unroll
  for (int q = 0; q < 8; q++) {
    int idx = q * 256 + tid;
    int j0 = idx >> 4, kq = idx & 15;
    float4 v0 = *(const float4*)(W + (long)j0 * DD + kq * 8);
    float4 v1 = *(const float4*)(W + (long)j0 * DD + kq * 8 + 4);
    float v[8] = {v0.x, v0.y, v0.z, v0.w, v1.x, v1.y, v1.z, v1.w};
    bf16x8 b;
#pragma unroll
    for (int jj = 0; jj < 8; jj++) b[jj] = f2bf(v[jj]);
    *(bf16x8*)((char*)Bs + j0 * 256 + ((kq * 16) ^ ((j0 & 7) << 4))) = b;
  }
  __syncthreads();

  const int wid = tid >> 6, lane = tid & 63;
  const int la = lane & 15, lb = lane >> 4;

  bf16x8 afr[4];
#pragma unroll
  for (int kc = 0; kc < 4; kc++) {
    int r = wid * 16 + la;
    int cb2 = (kc * 32 + lb * 8) * 2;
    afr[kc] = *(bf16x8*)((char*)As + r * 256 + (cb2 ^ ((la & 7) << 4)));
  }

  f32x4 acc[8];
#pragma unroll
  for (int cb = 0; cb < 8; cb++) acc[cb] = (f32x4){0.f, 0.f, 0.f, 0.f};

#pragma unroll
  for (int cb = 0; cb < 8; cb++) {
    int j = cb * 16 + la;
#pragma unroll
    for (int kc = 0; kc < 4; kc++) {
      int cb2 = (kc * 32 + lb * 8) * 2;
      bf16x8 bfr = *(bf16x8*)((char*)Bs + j * 256 + (cb2 ^ ((la & 7) << 4)));
      acc[cb] = __builtin_amdgcn_mfma_f32_16x16x32_bf16(afr[kc], bfr, acc[cb], 0, 0, 0);
    }
  }

  float sa[4] = {0,0,0,0}, da[4] = {0,0,0,0}, r0s[4] = {0,0,0,0}, r1s[4] = {0,0,0,0};
#pragma unroll
  for (int cb = 0; cb < 8; cb++) {
    int c = cb * 16 + la;
    float wa0 = Wa[c], wa1 = Wa[DD + c], w0 = wr[c], w1 = wr[DD + c];
#pragma unroll
    for (int rg = 0; rg < 4; rg++) {
      float zv = acc[cb][rg];
      sa[rg]  += zv * wa0; da[rg]  += zv * wa1;
      r0s[rg] += zv * w0;  r1s[rg] += zv * w1;
    }
  }
#pragma unroll
  for (int rg = 0; rg < 4; rg++) {
#pragma unroll
    for (int o = 1; o < 16; o <<= 1) {
      sa[rg]  += __shfl_xor(sa[rg], o);
      da[rg]  += __shfl_xor(da[rg], o);
      r0s[rg] += __shfl_xor(r0s[rg], o);
      r1s[rg] += __shfl_xor(r1s[rg], o);
    }
    int row = row0 + wid * 16 + lb * 4 + rg;
    if (la == 0 && row < NN) {
      s[row] = sa[rg]; dv[row] = da[rg]; zr0[row] = r0s[rg]; zr1[row] = r1s[rg];
    }
  }

  __syncthreads();
  __half* zl = (__half*)smem;             // 64 x 132 halfs
#pragma unroll
  for (int cb = 0; cb < 8; cb++) {
#pragma unroll
    for (int rg = 0; rg < 4; rg++) {
      int r = wid * 16 + lb * 4 + rg, c = cb * 16 + la;
      zl[r * 132 + c] = __float2half(acc[cb][rg]);
    }
  }
  __syncthreads();
  {
    int r = tid >> 2, c0 = (tid & 3) * 32;
    int row = row0 + r;
    if (row < NN) {
      const __half* src = zl + r * 132 + c0;
      int4 a0 = *(const int4*)(src);
      int4 a1 = *(const int4*)(src + 8);
      int4 a2 = *(const int4*)(src + 16);
      int4 a3 = *(const int4*)(src + 24);
      __half* dst = z + (long)row * DD + c0;
      *(int4*)(dst)      = a0;
      *(int4*)(dst + 8)  = a1;
      *(int4*)(dst + 16) = a2;
      *(int4*)(dst + 24) = a3;
    }
  }
}

// ---- K2: softmax + row/col pre-BN outputs + per-block BN partial sums ----
// 256 threads = 4 waves; each wave handles 4 nodes; block covers 16 nodes.
__global__ __launch_bounds__(256) void k2_main(
    const __half* __restrict__ z, const float* __restrict__ s,
    const float* __restrict__ dv, const float* __restrict__ zr0,
    const float* __restrict__ zr1, const int* __restrict__ nbr,
    const float* __restrict__ wc, const float* __restrict__ brp,
    const float* __restrict__ bcp,
    float* __restrict__ out, float* __restrict__ partials) {
  __shared__ float red[4][4];
  const int w = threadIdx.x >> 6, lane = threadIdx.x & 63;
  const float br0 = brp[0], bc0 = bcp[0];
  const __half2* z2 = (const __half2*)z;
  float pr = 0.f, pr2 = 0.f, pc = 0.f, pc2 = 0.f;

#pragma unroll
  for (int it = 0; it < 4; it++) {
    int i = blockIdx.x * 16 + w * 4 + it;     // < 30000 always
    float dvi = dv[i];
    float aw = 0.f; int base = 0;
    if (lane < KK) {
      int nk = nbr[i * KK + lane];
      float e = s[nk] + dvi;
      e = e > 0.f ? e : 0.01f * e;              // leaky_relu
      float mx = e;
#pragma unroll
      for (int o = 16; o; o >>= 1) mx = fmaxf(mx, __shfl_xor(mx, o, 32));
      float ex = __expf(e - mx);
      float sm = ex;
#pragma unroll
      for (int o = 16; o; o >>= 1) sm += __shfl_xor(sm, o, 32);
      float alpha = ex / sm;

      float t1 = alpha * zr1[nk];
      float t1n = __shfl_down(t1, 1, 32);
      if (lane < KK - 1) {
        float v = alpha * zr0[nk] + t1n + br0;
        out[(long)i * OUTW + lane] = v;
        pr += v; pr2 += v * v;
      }
      aw = alpha * wc[lane];
      base = nk * (DD / 2);
    }
    float ax = 0.f, ay = 0.f;
#pragma unroll
    for (int k = 0; k < KK; k++) {
      float a = __shfl(aw, k);
      int off = __shfl(base, k);
      float2 v = __half22float2(z2[off + lane]);
      ax += a * v.x; ay += a * v.y;
    }
    float c0 = ax + bc0, c1 = ay + bc0;
    long ob = (long)i * OUTW + 31 + 2 * lane;
    out[ob] = c0; out[ob + 1] = c1;
    pc += c0 + c1; pc2 += c0 * c0 + c1 * c1;
  }

#pragma unroll
  for (int o = 32; o; o >>= 1) {
    pr  += __shfl_xor(pr, o);  pr2 += __shfl_xor(pr2, o);
    pc  += __shfl_xor(pc, o);  pc2 += __shfl_xor(pc2, o);
  }
  if (lane == 0) { red[w][0] = pr; red[w][1] = pr2; red[w][2] = pc; red[w][3] = pc2; }
  __syncthreads();
  if (threadIdx.x < 4) {
    float v = red[0][threadIdx.x] + red[1][threadIdx.x] +
              red[2][threadIdx.x] + red[3][threadIdx.x];
    partials[(long)blockIdx.x * 4 + threadIdx.x] = v;
  }
}

// ---- K3: per-block redundant partial reduce -> BN coef; apply BN+ReLU ----
__global__ __launch_bounds__(256) void k3_fused(
    float* __restrict__ out, const float* __restrict__ partials,
    const float* __restrict__ gr, const float* __restrict__ betar,
    const float* __restrict__ gc, const float* __restrict__ betac) {
  __shared__ float red[4][4];
  __shared__ float coefs[4];
  const int w = threadIdx.x >> 6, lane = threadIdx.x & 63;

  float v0 = 0.f, v1 = 0.f, v2 = 0.f, v3 = 0.f;
  for (int idx = threadIdx.x; idx < K2BLKS; idx += 256) {
    float4 p = ((const float4*)partials)[idx];
    v0 += p.x; v1 += p.y; v2 += p.z; v3 += p.w;
  }
#pragma unroll
  for (int o = 32; o; o >>= 1) {
    v0 += __shfl_xor(v0, o); v1 += __shfl_xor(v1, o);
    v2 += __shfl_xor(v2, o); v3 += __shfl_xor(v3, o);
  }
  if (lane == 0) { red[w][0] = v0; red[w][1] = v1; red[w][2] = v2; red[w][3] = v3; }
  __syncthreads();
  if (threadIdx.x == 0) {
    float sr  = red[0][0] + red[1][0] + red[2][0] + red[3][0];
    float sr2 = red[0][1] + red[1][1] + red[2][1] + red[3][1];
    float sc  = red[0][2] + red[1][2] + red[2][2] + red[3][2];
    float sc2 = red[0][3] + red[1][3] + red[2][3] + red[3][3];
    const float cntR = (float)NN * 31.0f, cntC = (float)NN * 128.0f;
    float mR = sr / cntR,  vR = sr2 / cntR - mR * mR;
    float mC = sc / cntC,  vC = sc2 / cntC - mC * mC;
    float scR = gr[0] * rsqrtf(vR + 1e-5f);
    float scC = gc[0] * rsqrtf(vC + 1e-5f);
    coefs[0] = scR; coefs[1] = betar[0] - mR * scR;
    coefs[2] = scC; coefs[3] = betac[0] - mC * scC;
  }
  __syncthreads();
  const float scR = coefs[0], shR = coefs[1], scC = coefs[2], shC = coefs[3];

  const int TOT4 = NN * OUTW / 4;   // 1,192,500 exactly
  float4* o4 = (float4*)out;
  for (int f = blockIdx.x * 256 + threadIdx.x; f < TOT4; f += K3BLKS * 256) {
    float4 x = o4[f];
    int j = (4 * f) % OUTW;
    float r[4] = {x.x, x.y, x.z, x.w};
#pragma unroll
    for (int e = 0; e < 4; e++) {
      bool isRow = j < 31;
      r[e] = fmaxf((isRow ? scR : scC) * r[e] + (isRow ? shR : shC), 0.f);
      j = (j == OUTW - 1) ? 0 : j + 1;
    }
    o4[f] = make_float4(r[0], r[1], r[2], r[3]);
  }
}

extern "C" void kernel_launch(void* const* d_in, const int* in_sizes, int n_in,
                              void* d_out, int out_size, void* d_ws, size_t ws_size,
                              hipStream_t stream) {
  const float* h     = (const float*)d_in[0];
  const float* Wfc   = (const float*)d_in[1];
  const float* Wa    = (const float*)d_in[2];
  const float* wr    = (const float*)d_in[3];
  const float* br    = (const float*)d_in[4];
  const float* gr    = (const float*)d_in[5];
  const float* betar = (const float*)d_in[6];
  const float* wc    = (const float*)d_in[7];
  const float* bc    = (const float*)d_in[8];
  const float* gc    = (const float*)d_in[9];
  const float* betac = (const float*)d_in[10];
  const int*   nbr   = (const int*)d_in[11];
  float* out = (float*)d_out;

  float* ws   = (float*)d_ws;
  __half* z   = (__half*)ws;             // NN*DD halfs
  float* s    = ws + (long)NN * DD / 2;  // NN
  float* dv   = s  + NN;
  float* zr0  = dv + NN;
  float* zr1  = zr0 + NN;
  float* partials = zr1 + NN;            // K2BLKS*4

  k1_gemm<<<(NN + 63) / 64, 256, 0, stream>>>(h, Wfc, Wa, wr, z, s, dv, zr0, zr1);
  k2_main<<<K2BLKS, 256, 0, stream>>>(z, s, dv, zr0, zr1, nbr, wc, br, bc, out, partials);
  k3_fused<<<K3BLKS, 256, 0, stream>>>(out, partials, gr, betar, gc, betac);
}

// Round 7
// 60.591 us; speedup vs baseline: 6.8061x; 1.0551x over previous
//
#include <hip/hip_runtime.h>
#include <hip/hip_fp16.h>

#define NN 30000
#define DD 128
#define KK 32
#define OUTW 159   // 31 + 128
#define K2BLKS 1875   // 16 nodes per block
#define K3BLKS 1024

typedef __attribute__((ext_vector_type(8))) short bf16x8;
typedef __attribute__((ext_vector_type(4))) float f32x4;

static __device__ inline short f2bf(float f) {
  union { float f; unsigned u; } x; x.f = f;
  unsigned r = x.u + 0x7fffu + ((x.u >> 16) & 1u);   // RNE
  return (short)(r >> 16);
}

// ---------------- K1: z = h @ Wfc^T via MFMA bf16; fused dots; z -> fp16 --
__global__ __launch_bounds__(256) void k1_gemm(
    const float* __restrict__ h, const float* __restrict__ W,
    const float* __restrict__ Wa, const float* __restrict__ wr,
    __half* __restrict__ z, float* __restrict__ s, float* __restrict__ dv,
    float* __restrict__ zr0, float* __restrict__ zr1) {
  __shared__ char smem[48 * 1024];
  short* As = (short*)smem;               // 64*128 bf16, row stride 256B
  short* Bs = (short*)(smem + 16 * 1024); // 128*128 bf16, row stride 256B
  const int tid = threadIdx.x;
  const int row0 = blockIdx.x * 64;

#pragma unroll
  for (int q = 0; q < 4; q++) {
    int idx = q * 256 + tid;
    int r = idx >> 4, kq = idx & 15;
    int row = row0 + r;
    float v[8];
    if (row < NN) {
      float4 v0 = *(const float4*)(h + (long)row * DD + kq * 8);
      float4 v1 = *(const float4*)(h + (long)row * DD + kq * 8 + 4);
      v[0]=v0.x; v[1]=v0.y; v[2]=v0.z; v[3]=v0.w;
      v[4]=v1.x; v[5]=v1.y; v[6]=v1.z; v[7]=v1.w;
    } else {
#pragma unroll
      for (int j = 0; j < 8; j++) v[j] = 0.f;
    }
    bf16x8 b;
#pragma unroll
    for (int j = 0; j < 8; j++) b[j] = f2bf(v[j]);
    *(bf16x8*)((char*)As + r * 256 + ((kq * 16) ^ ((r & 7) << 4))) = b;
  }
#pragma unroll
  for (int q = 0; q < 8; q++) {
    int idx = q * 256 + tid;
    int j0 = idx >> 4, kq = idx & 15;
    float4 v0 = *(const float4*)(W + (long)j0 * DD + kq * 8);
    float4 v1 = *(const float4*)(W + (long)j0 * DD + kq * 8 + 4);
    float v[8] = {v0.x, v0.y, v0.z, v0.w, v1.x, v1.y, v1.z, v1.w};
    bf16x8 b;
#pragma unroll
    for (int jj = 0; jj < 8; jj++) b[jj] = f2bf(v[jj]);
    *(bf16x8*)((char*)Bs + j0 * 256 + ((kq * 16) ^ ((j0 & 7) << 4))) = b;
  }
  __syncthreads();

  const int wid = tid >> 6, lane = tid & 63;
  const int la = lane & 15, lb = lane >> 4;

  bf16x8 afr[4];
#pragma unroll
  for (int kc = 0; kc < 4; kc++) {
    int r = wid * 16 + la;
    int cb2 = (kc * 32 + lb * 8) * 2;
    afr[kc] = *(bf16x8*)((char*)As + r * 256 + (cb2 ^ ((la & 7) << 4)));
  }

  f32x4 acc[8];
#pragma unroll
  for (int cb = 0; cb < 8; cb++) acc[cb] = (f32x4){0.f, 0.f, 0.f, 0.f};

#pragma unroll
  for (int cb = 0; cb < 8; cb++) {
    int j = cb * 16 + la;
#pragma unroll
    for (int kc = 0; kc < 4; kc++) {
      int cb2 = (kc * 32 + lb * 8) * 2;
      bf16x8 bfr = *(bf16x8*)((char*)Bs + j * 256 + (cb2 ^ ((la & 7) << 4)));
      acc[cb] = __builtin_amdgcn_mfma_f32_16x16x32_bf16(afr[kc], bfr, acc[cb], 0, 0, 0);
    }
  }

  float sa[4] = {0,0,0,0}, da[4] = {0,0,0,0}, r0s[4] = {0,0,0,0}, r1s[4] = {0,0,0,0};
#pragma unroll
  for (int cb = 0; cb < 8; cb++) {
    int c = cb * 16 + la;
    float wa0 = Wa[c], wa1 = Wa[DD + c], w0 = wr[c], w1 = wr[DD + c];
#pragma unroll
    for (int rg = 0; rg < 4; rg++) {
      float zv = acc[cb][rg];
      sa[rg]  += zv * wa0; da[rg]  += zv * wa1;
      r0s[rg] += zv * w0;  r1s[rg] += zv * w1;
    }
  }
#pragma unroll
  for (int rg = 0; rg < 4; rg++) {
#pragma unroll
    for (int o = 1; o < 16; o <<= 1) {
      sa[rg]  += __shfl_xor(sa[rg], o);
      da[rg]  += __shfl_xor(da[rg], o);
      r0s[rg] += __shfl_xor(r0s[rg], o);
      r1s[rg] += __shfl_xor(r1s[rg], o);
    }
    int row = row0 + wid * 16 + lb * 4 + rg;
    if (la == 0 && row < NN) {
      s[row] = sa[rg]; dv[row] = da[rg]; zr0[row] = r0s[rg]; zr1[row] = r1s[rg];
    }
  }

  __syncthreads();
  __half* zl = (__half*)smem;             // 64 x 132 halfs
#pragma unroll
  for (int cb = 0; cb < 8; cb++) {
#pragma unroll
    for (int rg = 0; rg < 4; rg++) {
      int r = wid * 16 + lb * 4 + rg, c = cb * 16 + la;
      zl[r * 132 + c] = __float2half(acc[cb][rg]);
    }
  }
  __syncthreads();
  {
    int r = tid >> 2, c0 = (tid & 3) * 32;
    int row = row0 + r;
    if (row < NN) {
      const __half* src = zl + r * 132 + c0;
      int4 a0 = *(const int4*)(src);
      int4 a1 = *(const int4*)(src + 8);
      int4 a2 = *(const int4*)(src + 16);
      int4 a3 = *(const int4*)(src + 24);
      __half* dst = z + (long)row * DD + c0;
      *(int4*)(dst)      = a0;
      *(int4*)(dst + 8)  = a1;
      *(int4*)(dst + 16) = a2;
      *(int4*)(dst + 24) = a3;
    }
  }
}

// ---- K2: softmax + row/col pre-BN outputs + per-block BN partial sums ----
// 256 threads = 4 waves; each wave handles 4 nodes sequentially.
// Col gather: lane=(p=lane>>4, m=lane&15); iter t loads row k=4t+p,
// halves [m*8, m*8+8) as one int4 -> 8 VMEM instrs/node, 16B/lane.
__global__ __launch_bounds__(256) void k2_main(
    const __half* __restrict__ z, const float* __restrict__ s,
    const float* __restrict__ dv, const float* __restrict__ zr0,
    const float* __restrict__ zr1, const int* __restrict__ nbr,
    const float* __restrict__ wc, const float* __restrict__ brp,
    const float* __restrict__ bcp,
    float* __restrict__ out, float* __restrict__ partials) {
  __shared__ float red[4][4];
  const int w = threadIdx.x >> 6, lane = threadIdx.x & 63;
  const int p = lane >> 4, m = lane & 15;
  const float br0 = brp[0], bc0 = bcp[0];
  float pr = 0.f, pr2 = 0.f, pc = 0.f, pc2 = 0.f;

#pragma unroll
  for (int it = 0; it < 4; it++) {
    int i = blockIdx.x * 16 + w * 4 + it;     // < 30000 always
    float dvi = dv[i];
    float aw = 0.f; int base = 0;
    if (lane < KK) {
      int nk = nbr[i * KK + lane];
      float e = s[nk] + dvi;
      e = e > 0.f ? e : 0.01f * e;              // leaky_relu
      float mx = e;
#pragma unroll
      for (int o = 16; o; o >>= 1) mx = fmaxf(mx, __shfl_xor(mx, o, 32));
      float ex = __expf(e - mx);
      float sm = ex;
#pragma unroll
      for (int o = 16; o; o >>= 1) sm += __shfl_xor(sm, o, 32);
      float alpha = ex / sm;

      float t1 = alpha * zr1[nk];
      float t1n = __shfl_down(t1, 1, 32);
      if (lane < KK - 1) {
        float v = alpha * zr0[nk] + t1n + br0;
        out[(long)i * OUTW + lane] = v;
        pr += v; pr2 += v * v;
      }
      aw = alpha * wc[lane];
      base = nk * DD;                          // in half units
    }

    float ac[8];
#pragma unroll
    for (int e = 0; e < 8; e++) ac[e] = 0.f;
#pragma unroll
    for (int t = 0; t < 8; t++) {
      int k = 4 * t + p;
      float a = __shfl(aw, k);                 // ds_bpermute
      int off = __shfl(base, k);
      int4 raw = *(const int4*)(z + off + m * 8);
      const __half2* hp = (const __half2*)&raw;
      float2 f0 = __half22float2(hp[0]);
      float2 f1 = __half22float2(hp[1]);
      float2 f2 = __half22float2(hp[2]);
      float2 f3 = __half22float2(hp[3]);
      ac[0] += a * f0.x; ac[1] += a * f0.y;
      ac[2] += a * f1.x; ac[3] += a * f1.y;
      ac[4] += a * f2.x; ac[5] += a * f2.y;
      ac[6] += a * f3.x; ac[7] += a * f3.y;
    }
#pragma unroll
    for (int e = 0; e < 8; e++) {
      ac[e] += __shfl_xor(ac[e], 16);
      ac[e] += __shfl_xor(ac[e], 32);
      ac[e] += bc0;
    }
    if (p == 0) {
      long ob = (long)i * OUTW + 31 + m * 8;
#pragma unroll
      for (int e = 0; e < 8; e++) {
        out[ob + e] = ac[e];
        pc += ac[e]; pc2 += ac[e] * ac[e];
      }
    }
  }

#pragma unroll
  for (int o = 32; o; o >>= 1) {
    pr  += __shfl_xor(pr, o);  pr2 += __shfl_xor(pr2, o);
    pc  += __shfl_xor(pc, o);  pc2 += __shfl_xor(pc2, o);
  }
  if (lane == 0) { red[w][0] = pr; red[w][1] = pr2; red[w][2] = pc; red[w][3] = pc2; }
  __syncthreads();
  if (threadIdx.x < 4) {
    float v = red[0][threadIdx.x] + red[1][threadIdx.x] +
              red[2][threadIdx.x] + red[3][threadIdx.x];
    partials[(long)blockIdx.x * 4 + threadIdx.x] = v;
  }
}

// ---- K3: per-block redundant partial reduce -> BN coef; apply BN+ReLU ----
__global__ __launch_bounds__(256) void k3_fused(
    float* __restrict__ out, const float* __restrict__ partials,
    const float* __restrict__ gr, const float* __restrict__ betar,
    const float* __restrict__ gc, const float* __restrict__ betac) {
  __shared__ float red[4][4];
  __shared__ float coefs[4];
  const int w = threadIdx.x >> 6, lane = threadIdx.x & 63;

  float v0 = 0.f, v1 = 0.f, v2 = 0.f, v3 = 0.f;
  for (int idx = threadIdx.x; idx < K2BLKS; idx += 256) {
    float4 p = ((const float4*)partials)[idx];
    v0 += p.x; v1 += p.y; v2 += p.z; v3 += p.w;
  }
#pragma unroll
  for (int o = 32; o; o >>= 1) {
    v0 += __shfl_xor(v0, o); v1 += __shfl_xor(v1, o);
    v2 += __shfl_xor(v2, o); v3 += __shfl_xor(v3, o);
  }
  if (lane == 0) { red[w][0] = v0; red[w][1] = v1; red[w][2] = v2; red[w][3] = v3; }
  __syncthreads();
  if (threadIdx.x == 0) {
    float sr  = red[0][0] + red[1][0] + red[2][0] + red[3][0];
    float sr2 = red[0][1] + red[1][1] + red[2][1] + red[3][1];
    float sc  = red[0][2] + red[1][2] + red[2][2] + red[3][2];
    float sc2 = red[0][3] + red[1][3] + red[2][3] + red[3][3];
    const float cntR = (float)NN * 31.0f, cntC = (float)NN * 128.0f;
    float mR = sr / cntR,  vR = sr2 / cntR - mR * mR;
    float mC = sc / cntC,  vC = sc2 / cntC - mC * mC;
    float scR = gr[0] * rsqrtf(vR + 1e-5f);
    float scC = gc[0] * rsqrtf(vC + 1e-5f);
    coefs[0] = scR; coefs[1] = betar[0] - mR * scR;
    coefs[2] = scC; coefs[3] = betac[0] - mC * scC;
  }
  __syncthreads();
  const float scR = coefs[0], shR = coefs[1], scC = coefs[2], shC = coefs[3];

  const int TOT4 = NN * OUTW / 4;   // 1,192,500 exactly
  float4* o4 = (float4*)out;
  for (int f = blockIdx.x * 256 + threadIdx.x; f < TOT4; f += K3BLKS * 256) {
    float4 x = o4[f];
    int j = (4 * f) % OUTW;
    float r[4] = {x.x, x.y, x.z, x.w};
#pragma unroll
    for (int e = 0; e < 4; e++) {
      bool isRow = j < 31;
      r[e] = fmaxf((isRow ? scR : scC) * r[e] + (isRow ? shR : shC), 0.f);
      j = (j == OUTW - 1) ? 0 : j + 1;
    }
    o4[f] = make_float4(r[0], r[1], r[2], r[3]);
  }
}

extern "C" void kernel_launch(void* const* d_in, const int* in_sizes, int n_in,
                              void* d_out, int out_size, void* d_ws, size_t ws_size,
                              hipStream_t stream) {
  const float* h     = (const float*)d_in[0];
  const float* Wfc   = (const float*)d_in[1];
  const float* Wa    = (const float*)d_in[2];
  const float* wr    = (const float*)d_in[3];
  const float* br    = (const float*)d_in[4];
  const float* gr    = (const float*)d_in[5];
  const float* betar = (const float*)d_in[6];
  const float* wc    = (const float*)d_in[7];
  const float* bc    = (const float*)d_in[8];
  const float* gc    = (const float*)d_in[9];
  const float* betac = (const float*)d_in[10];
  const int*   nbr   = (const int*)d_in[11];
  float* out = (float*)d_out;

  float* ws   = (float*)d_ws;
  __half* z   = (__half*)ws;             // NN*DD halfs
  float* s    = ws + (long)NN * DD / 2;  // NN
  float* dv   = s  + NN;
  float* zr0  = dv + NN;
  float* zr1  = zr0 + NN;
  float* partials = zr1 + NN;            // K2BLKS*4

  k1_gemm<<<(NN + 63) / 64, 256, 0, stream>>>(h, Wfc, Wa, wr, z, s, dv, zr0, zr1);
  k2_main<<<K2BLKS, 256, 0, stream>>>(z, s, dv, zr0, zr1, nbr, wc, br, bc, out, partials);
  k3_fused<<<K3BLKS, 256, 0, stream>>>(out, partials, gr, betar, gc, betac);
}